// Round 1
// baseline (491.337 us; speedup 1.0000x reference)
//
#include <hip/hip_runtime.h>
#include <hip/hip_bf16.h>

// GroupSupConLoss: loss = mean_i[ lse_i - mean_pos_i ] over anchors with positives.
// sim = E E^T / tau, B=8192, D=1024, tau=0.1.
// Strategy: bf16-cast E, fused MFMA GEMM (128x128 tile) + per-row exp/pos
// reduction epilogue (never materialize sim), atomicAdd row partials, tiny
// finalize kernel.

#define NROWS 8192
#define DIM   1024
#define TAU_INV 10.0f

#define BM 128
#define BN 128
#define BK 64

typedef __attribute__((ext_vector_type(8))) short short8;
typedef __attribute__((ext_vector_type(4))) float f32x4;

__global__ void convert_bf16_kernel(const float* __restrict__ in,
                                    unsigned short* __restrict__ out, int n4) {
    int i = blockIdx.x * blockDim.x + threadIdx.x;
    const int stride = gridDim.x * blockDim.x;
    for (; i < n4; i += stride) {
        float4 v = ((const float4*)in)[i];
        __hip_bfloat16 b0 = __float2bfloat16(v.x);
        __hip_bfloat16 b1 = __float2bfloat16(v.y);
        __hip_bfloat16 b2 = __float2bfloat16(v.z);
        __hip_bfloat16 b3 = __float2bfloat16(v.w);
        ushort4 o;
        o.x = *(unsigned short*)&b0;
        o.y = *(unsigned short*)&b1;
        o.z = *(unsigned short*)&b2;
        o.w = *(unsigned short*)&b3;
        ((ushort4*)out)[i] = o;
    }
}

__device__ __forceinline__ void gload_lds16(const short* g, short* l) {
    __builtin_amdgcn_global_load_lds(
        (const __attribute__((address_space(1))) unsigned*)g,
        (__attribute__((address_space(3))) unsigned*)l, 16, 0, 0);
}

__launch_bounds__(256)
__global__ void simloss_kernel(const unsigned short* __restrict__ ebf_u,
                               const int* __restrict__ labels,
                               float* __restrict__ exp_sum,
                               float* __restrict__ pos_sum,
                               float* __restrict__ pos_cnt) {
    __shared__ short Abuf[BM * BK];   // 16 KiB, linear (global_load_lds needs linear dst)
    __shared__ short Bbuf[BN * BK];   // 16 KiB

    const int tid  = threadIdx.x;
    const int lane = tid & 63;
    const int wid  = tid >> 6;   // 0..3
    const int wrow = wid >> 1;   // 0..1  (64-row half owned by this wave)
    const int wcol = wid & 1;    // 0..1

    const int tile = blockIdx.x;
    const int ti = tile >> 6;    // row tile 0..63
    const int tj = tile & 63;    // col tile 0..63
    const int i0 = ti * BM;
    const int j0 = tj * BN;

    const short* eg = (const short*)ebf_u;

    f32x4 acc[4][4];
#pragma unroll
    for (int m = 0; m < 4; ++m)
#pragma unroll
        for (int n = 0; n < 4; ++n)
            acc[m][n] = (f32x4)0.0f;

    // staging geometry: 1 KiB chunk = 8 rows x 64 bf16; lane l -> row l/8, 16B group l%8
    const int l8 = lane >> 3;   // 0..7
    const int c8 = lane & 7;    // 0..7

#pragma unroll 1
    for (int kt = 0; kt < DIM / BK; ++kt) {
        const int k0 = kt * BK;
        // ---- stage A and B tiles (each wave: 4 chunks of each) ----
#pragma unroll
        for (int c = 0; c < 4; ++c) {
            const int chunk = wid * 4 + c;          // 0..15
            const int row = chunk * 8 + l8;         // 0..127
            const int kcol = k0 + c8 * 8;
            gload_lds16(eg + (size_t)(i0 + row) * DIM + kcol, Abuf + chunk * 512);
            gload_lds16(eg + (size_t)(j0 + row) * DIM + kcol, Bbuf + chunk * 512);
        }
        __syncthreads();

        // ---- MFMA on the staged tile ----
#pragma unroll
        for (int ks = 0; ks < 2; ++ks) {
            const int kb = ks * 32 + (lane >> 4) * 8;   // element offset within row
            short8 af[4], bf[4];
#pragma unroll
            for (int m = 0; m < 4; ++m) {
                const int r = wrow * 64 + m * 16 + (lane & 15);
                af[m] = *(const short8*)(Abuf + r * BK + kb);
            }
#pragma unroll
            for (int n = 0; n < 4; ++n) {
                const int r = wcol * 64 + n * 16 + (lane & 15);
                bf[n] = *(const short8*)(Bbuf + r * BK + kb);
            }
#pragma unroll
            for (int m = 0; m < 4; ++m)
#pragma unroll
                for (int n = 0; n < 4; ++n)
                    acc[m][n] = __builtin_amdgcn_mfma_f32_16x16x32_bf16(
                        af[m], bf[n], acc[m][n], 0, 0, 0);
        }
        __syncthreads();
    }

    // ---- fused epilogue: per-row exp-sum / pos-sum / pos-count ----
    // C/D layout (m89-verified): col = lane&15, row = (lane>>4)*4 + reg
    const int rowbase = i0 + wrow * 64;
    const int colbase = j0 + wcol * 64;

    int lc[4];
#pragma unroll
    for (int n = 0; n < 4; ++n)
        lc[n] = labels[colbase + n * 16 + (lane & 15)];

#pragma unroll
    for (int m = 0; m < 4; ++m) {
#pragma unroll
        for (int r = 0; r < 4; ++r) {
            const int row = rowbase + m * 16 + (lane >> 4) * 4 + r;
            const int lr = labels[row];
            float e = 0.0f, p = 0.0f, c = 0.0f;
#pragma unroll
            for (int n = 0; n < 4; ++n) {
                const int col = colbase + n * 16 + (lane & 15);
                const float s = acc[m][n][r] * TAU_INV;
                const bool diag = (row == col);
                e += diag ? 0.0f : __expf(s);
                const bool same = (lr == lc[n]) && !diag;
                p += same ? s : 0.0f;
                c += same ? 1.0f : 0.0f;
            }
            // reduce across the 16 lanes sharing this row (lane&15 varies)
#pragma unroll
            for (int off = 1; off < 16; off <<= 1) {
                e += __shfl_xor(e, off);
                p += __shfl_xor(p, off);
                c += __shfl_xor(c, off);
            }
            if ((lane & 15) == 0) {
                atomicAdd(&exp_sum[row], e);
                atomicAdd(&pos_sum[row], p);
                atomicAdd(&pos_cnt[row], c);
            }
        }
    }
}

__global__ void finalize_kernel(const float* __restrict__ exp_sum,
                                const float* __restrict__ pos_sum,
                                const float* __restrict__ pos_cnt,
                                float* __restrict__ out) {
    __shared__ float s_l[4];
    __shared__ float s_c[4];
    float lsum = 0.0f, csum = 0.0f;
    for (int i = threadIdx.x; i < NROWS; i += blockDim.x) {
        const float c = pos_cnt[i];
        const bool has = c > 0.5f;
        const float li = logf(exp_sum[i]) - pos_sum[i] / fmaxf(c, 1.0f);
        lsum += has ? li : 0.0f;
        csum += has ? 1.0f : 0.0f;
    }
#pragma unroll
    for (int off = 1; off < 64; off <<= 1) {
        lsum += __shfl_xor(lsum, off);
        csum += __shfl_xor(csum, off);
    }
    const int w = threadIdx.x >> 6;
    if ((threadIdx.x & 63) == 0) { s_l[w] = lsum; s_c[w] = csum; }
    __syncthreads();
    if (threadIdx.x == 0) {
        float L = 0.0f, C = 0.0f;
        for (int i = 0; i < 4; ++i) { L += s_l[i]; C += s_c[i]; }
        out[0] = L / fmaxf(C, 1.0f);
    }
}

extern "C" void kernel_launch(void* const* d_in, const int* in_sizes, int n_in,
                              void* d_out, int out_size, void* d_ws, size_t ws_size,
                              hipStream_t stream) {
    const float* emb   = (const float*)d_in[0];
    const int* labels  = (const int*)d_in[1];
    float* out         = (float*)d_out;

    char* ws = (char*)d_ws;
    unsigned short* ebf = (unsigned short*)ws;                       // 16 MiB
    float* exp_sum = (float*)(ws + (size_t)NROWS * DIM * 2);         // 32 KiB
    float* pos_sum = exp_sum + NROWS;
    float* pos_cnt = exp_sum + 2 * NROWS;

    hipMemsetAsync(exp_sum, 0, 3 * NROWS * sizeof(float), stream);
    convert_bf16_kernel<<<1024, 256, 0, stream>>>(emb, ebf, NROWS * DIM / 4);
    simloss_kernel<<<(NROWS / BM) * (NROWS / BN), 256, 0, stream>>>(
        ebf, labels, exp_sum, pos_sum, pos_cnt);
    finalize_kernel<<<1, 256, 0, stream>>>(exp_sum, pos_sum, pos_cnt, out);
}

// Round 4
// 368.132 us; speedup vs baseline: 1.3347x; 1.3347x over previous
//
#include <hip/hip_runtime.h>
#include <hip/hip_bf16.h>

// GroupSupConLoss: loss = mean_i[ lse_i - mean_pos_i ] over anchors with positives.
// sim = E E^T / tau, B=8192, D=1024, tau=0.1.
// R2: (a) exploit symmetry -- only tiles ti<=tj (2080 blocks vs 4096), off-diag
// tiles feed both row-side and col-side reductions; (b) LDS XOR swizzle via
// pre-swizzled global source (linear global_load_lds dst, swizzled ds_read)
// to kill the 16-way bank conflict (was 5e7 conflict cycles).

#define NROWS 8192
#define DIM   1024
#define TAU_INV 10.0f

#define BM 128
#define BN 128
#define BK 64
#define NTILE (NROWS / BM)          // 64
#define NBLOCKS (NTILE * (NTILE + 1) / 2)  // 2080

typedef __attribute__((ext_vector_type(8))) short short8;
typedef __attribute__((ext_vector_type(4))) float f32x4;

__global__ void convert_bf16_kernel(const float* __restrict__ in,
                                    unsigned short* __restrict__ out, int n4) {
    int i = blockIdx.x * blockDim.x + threadIdx.x;
    const int stride = gridDim.x * blockDim.x;
    for (; i < n4; i += stride) {
        float4 v = ((const float4*)in)[i];
        __hip_bfloat16 b0 = __float2bfloat16(v.x);
        __hip_bfloat16 b1 = __float2bfloat16(v.y);
        __hip_bfloat16 b2 = __float2bfloat16(v.z);
        __hip_bfloat16 b3 = __float2bfloat16(v.w);
        ushort4 o;
        o.x = *(unsigned short*)&b0;
        o.y = *(unsigned short*)&b1;
        o.z = *(unsigned short*)&b2;
        o.w = *(unsigned short*)&b3;
        ((ushort4*)out)[i] = o;
    }
}

__device__ __forceinline__ void gload_lds16(const short* g, short* l) {
    __builtin_amdgcn_global_load_lds(
        (const __attribute__((address_space(1))) unsigned*)g,
        (__attribute__((address_space(3))) unsigned*)l, 16, 0, 0);
}

__launch_bounds__(256)
__global__ void simloss_kernel(const unsigned short* __restrict__ ebf_u,
                               const int* __restrict__ labels,
                               float* __restrict__ exp_sum,
                               float* __restrict__ pos_sum,
                               float* __restrict__ pos_cnt) {
    __shared__ short Abuf[BM * BK];   // 16 KiB, linear dst (global_load_lds)
    __shared__ short Bbuf[BN * BK];   // 16 KiB

    const int tid  = threadIdx.x;
    const int lane = tid & 63;
    const int wid  = tid >> 6;   // 0..3
    const int wrow = wid >> 1;   // 0..1
    const int wcol = wid & 1;    // 0..1

    // decode blockIdx -> upper-triangular (ti, tj), ti <= tj
    int u = blockIdx.x, ti = 0, rowlen = NTILE;
    while (u >= rowlen) { u -= rowlen; ++ti; --rowlen; }
    const int tj = ti + u;
    const int i0 = ti * BM;
    const int j0 = tj * BN;
    const bool offdiag = (ti != tj);

    const short* eg = (const short*)ebf_u;

    f32x4 acc[4][4];
#pragma unroll
    for (int m = 0; m < 4; ++m)
#pragma unroll
        for (int n = 0; n < 4; ++n)
            acc[m][n] = (f32x4)0.0f;

    // staging geometry: 1 KiB chunk = 8 rows x 64 bf16; lane l -> row l>>3,
    // LDS 16B slot l&7.  Global column group is XOR-swizzled: c_src = (l&7)^(l>>3)
    // so that a swizzled ds_read (below) is bank-conflict-free while the LDS
    // destination stays linear (global_load_lds requirement).
    const int l8 = lane >> 3;   // row in chunk, 0..7
    const int c8 = lane & 7;    // LDS 16B slot, 0..7
    const int csrc = c8 ^ l8;   // swizzled global column group

#pragma unroll 1
    for (int kt = 0; kt < DIM / BK; ++kt) {
        const int k0 = kt * BK;
#pragma unroll
        for (int c = 0; c < 4; ++c) {
            const int chunk = wid * 4 + c;          // 0..15
            const int row = chunk * 8 + l8;         // 0..127
            const int kcol = k0 + csrc * 8;
            gload_lds16(eg + (size_t)(i0 + row) * DIM + kcol, Abuf + chunk * 512);
            gload_lds16(eg + (size_t)(j0 + row) * DIM + kcol, Bbuf + chunk * 512);
        }
        __syncthreads();

#pragma unroll
        for (int ks = 0; ks < 2; ++ks) {
            const int g = ks * 4 + (lane >> 4);     // column group 0..7
            short8 af[4], bf[4];
#pragma unroll
            for (int m = 0; m < 4; ++m) {
                const int r = wrow * 64 + m * 16 + (lane & 15);
                af[m] = *(const short8*)(Abuf + r * BK + ((g ^ (r & 7)) << 3));
            }
#pragma unroll
            for (int n = 0; n < 4; ++n) {
                const int r = wcol * 64 + n * 16 + (lane & 15);
                bf[n] = *(const short8*)(Bbuf + r * BK + ((g ^ (r & 7)) << 3));
            }
#pragma unroll
            for (int m = 0; m < 4; ++m)
#pragma unroll
                for (int n = 0; n < 4; ++n)
                    acc[m][n] = __builtin_amdgcn_mfma_f32_16x16x32_bf16(
                        af[m], bf[n], acc[m][n], 0, 0, 0);
        }
        __syncthreads();
    }

    // ---- fused epilogue ----
    // C/D layout: col = lane&15, row = (lane>>4)*4 + reg
    const int rowbase = i0 + wrow * 64;
    const int colbase = j0 + wcol * 64;

    int lc[4];
#pragma unroll
    for (int n = 0; n < 4; ++n)
        lc[n] = labels[colbase + n * 16 + (lane & 15)];

    float ecol[4] = {0, 0, 0, 0};
    float pcol[4] = {0, 0, 0, 0};
    float ccol[4] = {0, 0, 0, 0};

#pragma unroll
    for (int m = 0; m < 4; ++m) {
#pragma unroll
        for (int r = 0; r < 4; ++r) {
            const int row = rowbase + m * 16 + (lane >> 4) * 4 + r;
            const int lr = labels[row];
            float e = 0.0f, p = 0.0f, c = 0.0f;
#pragma unroll
            for (int n = 0; n < 4; ++n) {
                const int col = colbase + n * 16 + (lane & 15);
                const float s = acc[m][n][r] * TAU_INV;
                const bool diag = (row == col);
                const float ex = diag ? 0.0f : __expf(s);
                const bool same = (lr == lc[n]) && !diag;
                const float ps = same ? s : 0.0f;
                const float cs = same ? 1.0f : 0.0f;
                e += ex; p += ps; c += cs;
                ecol[n] += ex; pcol[n] += ps; ccol[n] += cs;
            }
#pragma unroll
            for (int off = 1; off < 16; off <<= 1) {
                e += __shfl_xor(e, off);
                p += __shfl_xor(p, off);
                c += __shfl_xor(c, off);
            }
            if ((lane & 15) == 0) {
                atomicAdd(&exp_sum[row], e);
                atomicAdd(&pos_sum[row], p);
                atomicAdd(&pos_cnt[row], c);
            }
        }
    }

    // col-side (mirror) contributions for off-diagonal tiles: row j gets
    // sum_i exp(s_ij) etc. (s symmetric, label mask symmetric).
    if (offdiag) {
#pragma unroll
        for (int n = 0; n < 4; ++n) {
#pragma unroll
            for (int off = 16; off < 64; off <<= 1) {
                ecol[n] += __shfl_xor(ecol[n], off);
                pcol[n] += __shfl_xor(pcol[n], off);
                ccol[n] += __shfl_xor(ccol[n], off);
            }
            if (lane < 16) {
                const int row = colbase + n * 16 + lane;
                atomicAdd(&exp_sum[row], ecol[n]);
                atomicAdd(&pos_sum[row], pcol[n]);
                atomicAdd(&pos_cnt[row], ccol[n]);
            }
        }
    }
}

__global__ void finalize_kernel(const float* __restrict__ exp_sum,
                                const float* __restrict__ pos_sum,
                                const float* __restrict__ pos_cnt,
                                float* __restrict__ out) {
    __shared__ float s_l[4];
    __shared__ float s_c[4];
    float lsum = 0.0f, csum = 0.0f;
    for (int i = threadIdx.x; i < NROWS; i += blockDim.x) {
        const float c = pos_cnt[i];
        const bool has = c > 0.5f;
        const float li = logf(exp_sum[i]) - pos_sum[i] / fmaxf(c, 1.0f);
        lsum += has ? li : 0.0f;
        csum += has ? 1.0f : 0.0f;
    }
#pragma unroll
    for (int off = 1; off < 64; off <<= 1) {
        lsum += __shfl_xor(lsum, off);
        csum += __shfl_xor(csum, off);
    }
    const int w = threadIdx.x >> 6;
    if ((threadIdx.x & 63) == 0) { s_l[w] = lsum; s_c[w] = csum; }
    __syncthreads();
    if (threadIdx.x == 0) {
        float L = 0.0f, C = 0.0f;
        for (int i = 0; i < 4; ++i) { L += s_l[i]; C += s_c[i]; }
        out[0] = L / fmaxf(C, 1.0f);
    }
}

extern "C" void kernel_launch(void* const* d_in, const int* in_sizes, int n_in,
                              void* d_out, int out_size, void* d_ws, size_t ws_size,
                              hipStream_t stream) {
    const float* emb   = (const float*)d_in[0];
    const int* labels  = (const int*)d_in[1];
    float* out         = (float*)d_out;

    char* ws = (char*)d_ws;
    unsigned short* ebf = (unsigned short*)ws;                       // 16 MiB
    float* exp_sum = (float*)(ws + (size_t)NROWS * DIM * 2);         // 32 KiB
    float* pos_sum = exp_sum + NROWS;
    float* pos_cnt = exp_sum + 2 * NROWS;

    hipMemsetAsync(exp_sum, 0, 3 * NROWS * sizeof(float), stream);
    convert_bf16_kernel<<<1024, 256, 0, stream>>>(emb, ebf, NROWS * DIM / 4);
    simloss_kernel<<<NBLOCKS, 256, 0, stream>>>(ebf, labels, exp_sum, pos_sum, pos_cnt);
    finalize_kernel<<<1, 256, 0, stream>>>(exp_sum, pos_sum, pos_cnt, out);
}

// Round 5
// 291.832 us; speedup vs baseline: 1.6836x; 1.2614x over previous
//
#include <hip/hip_runtime.h>
#include <hip/hip_bf16.h>

// GroupSupConLoss: loss = mean_i[ lse_i - mean_pos_i ] over anchors with positives.
// sim = E E^T / tau, B=8192, D=1024, tau=0.1.
// R5: (a) 2-phase double-buffered K-loop (issue prefetch BEFORE compute, one
// barrier per iter) -- R4 was stage->drain->compute with zero overlap, pure
// latency-bound (MfmaUtil 9.5%, all pipes idle); (b) bijective XCD-aware tile
// swizzle (2080 tiles % 8 == 0) so each XCD's L2 keeps its A-band resident
// (FETCH was 259 MB for a 16 MB matrix).

#define NROWS 8192
#define DIM   1024
#define TAU_INV 10.0f

#define BM 128
#define BN 128
#define BK 64
#define NTILE (NROWS / BM)                 // 64
#define NBLOCKS (NTILE * (NTILE + 1) / 2)  // 2080
#define NKT (DIM / BK)                     // 16
#define TILE_ELEMS (BM * BK)               // 8192 shorts = 16 KiB

typedef __attribute__((ext_vector_type(8))) short short8;
typedef __attribute__((ext_vector_type(4))) float f32x4;

__global__ void convert_bf16_kernel(const float* __restrict__ in,
                                    unsigned short* __restrict__ out, int n4) {
    int i = blockIdx.x * blockDim.x + threadIdx.x;
    const int stride = gridDim.x * blockDim.x;
    for (; i < n4; i += stride) {
        float4 v = ((const float4*)in)[i];
        __hip_bfloat16 b0 = __float2bfloat16(v.x);
        __hip_bfloat16 b1 = __float2bfloat16(v.y);
        __hip_bfloat16 b2 = __float2bfloat16(v.z);
        __hip_bfloat16 b3 = __float2bfloat16(v.w);
        ushort4 o;
        o.x = *(unsigned short*)&b0;
        o.y = *(unsigned short*)&b1;
        o.z = *(unsigned short*)&b2;
        o.w = *(unsigned short*)&b3;
        ((ushort4*)out)[i] = o;
    }
}

__device__ __forceinline__ void gload_lds16(const short* g, short* l) {
    __builtin_amdgcn_global_load_lds(
        (const __attribute__((address_space(1))) unsigned*)g,
        (__attribute__((address_space(3))) unsigned*)l, 16, 0, 0);
}

__launch_bounds__(256)
__global__ void simloss_kernel(const unsigned short* __restrict__ ebf_u,
                               const int* __restrict__ labels,
                               float* __restrict__ exp_sum,
                               float* __restrict__ pos_sum,
                               float* __restrict__ pos_cnt) {
    // [2 buffers][A|B][BM*BK] = 64 KiB total (2 blocks/CU)
    __shared__ short lds[2 * 2 * TILE_ELEMS];

    const int tid  = threadIdx.x;
    const int lane = tid & 63;
    const int wid  = tid >> 6;   // 0..3
    const int wrow = wid >> 1;   // 0..1
    const int wcol = wid & 1;    // 0..1

    // XCD-aware bijective swizzle: 2080 % 8 == 0, each XCD gets a contiguous
    // 260-tile band of the upper triangle (A-panels stay in that XCD's L2).
    const int tile = (blockIdx.x & 7) * (NBLOCKS / 8) + (blockIdx.x >> 3);

    // decode tile -> upper-triangular (ti, tj), ti <= tj
    int u = tile, ti = 0, rowlen = NTILE;
    while (u >= rowlen) { u -= rowlen; ++ti; --rowlen; }
    const int tj = ti + u;
    const int i0 = ti * BM;
    const int j0 = tj * BN;
    const bool offdiag = (ti != tj);

    const short* eg = (const short*)ebf_u;

    f32x4 acc[4][4];
#pragma unroll
    for (int m = 0; m < 4; ++m)
#pragma unroll
        for (int n = 0; n < 4; ++n)
            acc[m][n] = (f32x4)0.0f;

    // staging geometry: 1 KiB chunk = 8 rows x 64 bf16; lane l -> row l>>3,
    // LDS 16B slot l&7. Global column group XOR-swizzled (csrc = (l&7)^(l>>3))
    // so the swizzled ds_read below is bank-conflict-free while the LDS dst
    // stays linear (global_load_lds requirement). Verified R4: conflicts -> 0.
    const int l8 = lane >> 3;
    const int c8 = lane & 7;
    const int csrc = c8 ^ l8;

    const size_t arow = (size_t)(i0 + /*row*/ 0) * DIM;  // bases folded below

    // ---- prologue: stage K-tile 0 into buffer 0 ----
    {
        const int kcol = csrc * 8;
#pragma unroll
        for (int c = 0; c < 4; ++c) {
            const int chunk = wid * 4 + c;
            const int row = chunk * 8 + l8;
            gload_lds16(eg + (size_t)(i0 + row) * DIM + kcol, lds + chunk * 512);
            gload_lds16(eg + (size_t)(j0 + row) * DIM + kcol, lds + TILE_ELEMS + chunk * 512);
        }
    }
    __syncthreads();   // implies vmcnt drain: buffer 0 ready

#pragma unroll 1
    for (int kt = 0; kt < NKT; ++kt) {
        const int cur = kt & 1;
        short* curbuf = lds + cur * 2 * TILE_ELEMS;

        // ---- issue prefetch of K-tile kt+1 into the other buffer ----
        if (kt + 1 < NKT) {
            short* nxtbuf = lds + (cur ^ 1) * 2 * TILE_ELEMS;
            const int kcol = (kt + 1) * BK + csrc * 8;
#pragma unroll
            for (int c = 0; c < 4; ++c) {
                const int chunk = wid * 4 + c;
                const int row = chunk * 8 + l8;
                gload_lds16(eg + (size_t)(i0 + row) * DIM + kcol, nxtbuf + chunk * 512);
                gload_lds16(eg + (size_t)(j0 + row) * DIM + kcol, nxtbuf + TILE_ELEMS + chunk * 512);
            }
        }

        // ---- compute on current buffer (loads already resident) ----
#pragma unroll
        for (int ks = 0; ks < 2; ++ks) {
            const int g = ks * 4 + (lane >> 4);     // column group 0..7
            short8 af[4], bf[4];
#pragma unroll
            for (int m = 0; m < 4; ++m) {
                const int r = wrow * 64 + m * 16 + (lane & 15);
                af[m] = *(const short8*)(curbuf + r * BK + ((g ^ (r & 7)) << 3));
            }
#pragma unroll
            for (int n = 0; n < 4; ++n) {
                const int r = wcol * 64 + n * 16 + (lane & 15);
                bf[n] = *(const short8*)(curbuf + TILE_ELEMS + r * BK + ((g ^ (r & 7)) << 3));
            }
#pragma unroll
            for (int m = 0; m < 4; ++m)
#pragma unroll
                for (int n = 0; n < 4; ++n)
                    acc[m][n] = __builtin_amdgcn_mfma_f32_16x16x32_bf16(
                        af[m], bf[n], acc[m][n], 0, 0, 0);
        }

        // one barrier per iter: drains prefetch (next buffer ready) and
        // protects current buffer from being overwritten next iter.
        __syncthreads();
    }

    // ---- fused epilogue ----
    // C/D layout: col = lane&15, row = (lane>>4)*4 + reg
    const int rowbase = i0 + wrow * 64;
    const int colbase = j0 + wcol * 64;

    int lc[4];
#pragma unroll
    for (int n = 0; n < 4; ++n)
        lc[n] = labels[colbase + n * 16 + (lane & 15)];

    float ecol[4] = {0, 0, 0, 0};
    float pcol[4] = {0, 0, 0, 0};
    float ccol[4] = {0, 0, 0, 0};

#pragma unroll
    for (int m = 0; m < 4; ++m) {
#pragma unroll
        for (int r = 0; r < 4; ++r) {
            const int row = rowbase + m * 16 + (lane >> 4) * 4 + r;
            const int lr = labels[row];
            float e = 0.0f, p = 0.0f, c = 0.0f;
#pragma unroll
            for (int n = 0; n < 4; ++n) {
                const int col = colbase + n * 16 + (lane & 15);
                const float s = acc[m][n][r] * TAU_INV;
                const bool diag = (row == col);
                const float ex = diag ? 0.0f : __expf(s);
                const bool same = (lr == lc[n]) && !diag;
                const float ps = same ? s : 0.0f;
                const float cs = same ? 1.0f : 0.0f;
                e += ex; p += ps; c += cs;
                ecol[n] += ex; pcol[n] += ps; ccol[n] += cs;
            }
#pragma unroll
            for (int off = 1; off < 16; off <<= 1) {
                e += __shfl_xor(e, off);
                p += __shfl_xor(p, off);
                c += __shfl_xor(c, off);
            }
            if ((lane & 15) == 0) {
                atomicAdd(&exp_sum[row], e);
                atomicAdd(&pos_sum[row], p);
                atomicAdd(&pos_cnt[row], c);
            }
        }
    }

    // col-side (mirror) contributions for off-diagonal tiles: row j gets
    // sum_i exp(s_ij) etc. (s symmetric, label mask symmetric).
    if (offdiag) {
#pragma unroll
        for (int n = 0; n < 4; ++n) {
#pragma unroll
            for (int off = 16; off < 64; off <<= 1) {
                ecol[n] += __shfl_xor(ecol[n], off);
                pcol[n] += __shfl_xor(pcol[n], off);
                ccol[n] += __shfl_xor(ccol[n], off);
            }
            if (lane < 16) {
                const int row = colbase + n * 16 + lane;
                atomicAdd(&exp_sum[row], ecol[n]);
                atomicAdd(&pos_sum[row], pcol[n]);
                atomicAdd(&pos_cnt[row], ccol[n]);
            }
        }
    }
}

__global__ void finalize_kernel(const float* __restrict__ exp_sum,
                                const float* __restrict__ pos_sum,
                                const float* __restrict__ pos_cnt,
                                float* __restrict__ out) {
    __shared__ float s_l[4];
    __shared__ float s_c[4];
    float lsum = 0.0f, csum = 0.0f;
    for (int i = threadIdx.x; i < NROWS; i += blockDim.x) {
        const float c = pos_cnt[i];
        const bool has = c > 0.5f;
        const float li = logf(exp_sum[i]) - pos_sum[i] / fmaxf(c, 1.0f);
        lsum += has ? li : 0.0f;
        csum += has ? 1.0f : 0.0f;
    }
#pragma unroll
    for (int off = 1; off < 64; off <<= 1) {
        lsum += __shfl_xor(lsum, off);
        csum += __shfl_xor(csum, off);
    }
    const int w = threadIdx.x >> 6;
    if ((threadIdx.x & 63) == 0) { s_l[w] = lsum; s_c[w] = csum; }
    __syncthreads();
    if (threadIdx.x == 0) {
        float L = 0.0f, C = 0.0f;
        for (int i = 0; i < 4; ++i) { L += s_l[i]; C += s_c[i]; }
        out[0] = L / fmaxf(C, 1.0f);
    }
}

extern "C" void kernel_launch(void* const* d_in, const int* in_sizes, int n_in,
                              void* d_out, int out_size, void* d_ws, size_t ws_size,
                              hipStream_t stream) {
    const float* emb   = (const float*)d_in[0];
    const int* labels  = (const int*)d_in[1];
    float* out         = (float*)d_out;

    char* ws = (char*)d_ws;
    unsigned short* ebf = (unsigned short*)ws;                       // 16 MiB
    float* exp_sum = (float*)(ws + (size_t)NROWS * DIM * 2);         // 32 KiB
    float* pos_sum = exp_sum + NROWS;
    float* pos_cnt = exp_sum + 2 * NROWS;

    hipMemsetAsync(exp_sum, 0, 3 * NROWS * sizeof(float), stream);
    convert_bf16_kernel<<<1024, 256, 0, stream>>>(emb, ebf, NROWS * DIM / 4);
    simloss_kernel<<<NBLOCKS, 256, 0, stream>>>(ebf, labels, exp_sum, pos_sum, pos_cnt);
    finalize_kernel<<<1, 256, 0, stream>>>(exp_sum, pos_sum, pos_cnt, out);
}